// Round 6
// baseline (286.423 us; speedup 1.0000x reference)
//
#include <hip/hip_runtime.h>
#include <math.h>

// Problem constants
#define BB 2
#define HH 64
#define WW 64
#define DM 192
#define DI 384
#define NS 16
#define DTR 12
#define LL 4096
#define ROWS (BB*LL)   // 8192
#define NCHUNK 64
#define LCHUNK 64      // NCHUNK*LCHUNK == LL
#define NCOMB 512      // padded combined-weight rows (416 real) for 128-tile

typedef __attribute__((ext_vector_type(8))) short bf16x8;
typedef __attribute__((ext_vector_type(4))) float f32x4;

__device__ __forceinline__ float silu_f(float v) {
    return v / (1.0f + __expf(-v));
}

// fp32 -> bf16 (RNE) bit trick
__device__ __forceinline__ unsigned short f2bf(float f) {
    union { float f; unsigned int u; } c; c.f = f;
    unsigned int u = c.u;
    u += 0x7fffu + ((u >> 16) & 1u);
    return (unsigned short)(u >> 16);
}

// ---------------------------------------------------------------------------
// Cast a float array to bf16 (vectorized by 4). n must be /4.
// ---------------------------------------------------------------------------
__global__ __launch_bounds__(256) void cast_bf16(
    const float* __restrict__ in, unsigned short* __restrict__ out, int n4)
{
    int i = blockIdx.x * 256 + threadIdx.x;
    if (i >= n4) return;
    float4 v = ((const float4*)in)[i];
    ushort4 o;
    o.x = f2bf(v.x); o.y = f2bf(v.y); o.z = f2bf(v.z); o.w = f2bf(v.w);
    ((ushort4*)out)[i] = o;
}

// Cast the three static weights in one launch.
__global__ __launch_bounds__(256) void cast_weights(
    const float* __restrict__ w_in, const float* __restrict__ w_con,
    const float* __restrict__ w_out,
    unsigned short* __restrict__ w_in_bf, unsigned short* __restrict__ w_con_bf,
    unsigned short* __restrict__ w_out_bf)
{
    int i = blockIdx.x * 256 + threadIdx.x;   // float4 index, < 73728
    if (i >= 73728) return;
    const float4* src; ushort4* dst; int off;
    if (i < 36864)      { src = (const float4*)w_in;  dst = (ushort4*)w_in_bf;  off = i; }
    else if (i < 55296) { src = (const float4*)w_con; dst = (ushort4*)w_con_bf; off = i - 36864; }
    else                { src = (const float4*)w_out; dst = (ushort4*)w_out_bf; off = i - 55296; }
    float4 v = src[off];
    ushort4 o;
    o.x = f2bf(v.x); o.y = f2bf(v.y); o.z = f2bf(v.z); o.w = f2bf(v.w);
    dst[off] = o;
}

// ---------------------------------------------------------------------------
// Build combined weight Wc[512][384] in bf16:
//   rows 0..383:   sum_{r<12} dt_w[d][r] * x_proj_w[r][k]
//   rows 384..415: x_proj_w[12+c][k];  rows 416..511: 0
// ---------------------------------------------------------------------------
__global__ __launch_bounds__(256) void make_wcomb(
    const float* __restrict__ x_proj_w,   // (44,384)
    const float* __restrict__ dt_w,       // (384,12)
    unsigned short* __restrict__ wc)
{
    int idx = blockIdx.x * 256 + threadIdx.x;   // < 512*384
    if (idx >= NCOMB * DI) return;
    int row = idx / DI, k = idx - row * DI;
    float v = 0.f;
    if (row < 384) {
        const float* dw = dt_w + row * DTR;
        #pragma unroll
        for (int r = 0; r < DTR; ++r) v += dw[r] * x_proj_w[r * DI + k];
    } else if (row < 416) {
        v = x_proj_w[(12 + (row - 384)) * DI + k];
    }
    wc[idx] = f2bf(v);
}

// ---------------------------------------------------------------------------
// Shared epilogue semantics for both GEMMs:
// mode 0: N=768 split -> out0[row*384+col] raw (col<384), out1 = silu
// mode 1: plain out0[row*N+col]
// mode 2: col<384 -> out0 = softplus(v+bias[col]);
//         col in [384,400): B_n (n=col-384) -> out1[row*32 + (n&7)*4 + (n>>3)]
//         col in [400,416): C_n (n=col-400) -> out1[row*32 + (n&7)*4 + 2 + (n>>3)]
//         col>=416 dropped.
// ---------------------------------------------------------------------------
__device__ __forceinline__ void gemm_epilogue(
    int mode, int row, int col, int N, float v,
    const float* __restrict__ bias,
    float* __restrict__ out0, float* __restrict__ out1)
{
    if (mode == 0) {
        if (col < 384) out0[(size_t)row * 384 + col] = v;
        else           out1[(size_t)row * 384 + (col - 384)] = silu_f(v);
    } else if (mode == 1) {
        out0[(size_t)row * N + col] = v;
    } else {
        if (col < 384) {
            float a = v + bias[col];
            out0[(size_t)row * 384 + col] = (a > 20.f) ? a : log1pf(__expf(a));
        } else if (col < 416) {
            int idx = col - 384;
            int pos = (idx < 16) ? ((idx & 7) * 4 + (idx >> 3))
                                 : (((idx - 16) & 7) * 4 + 2 + ((idx - 16) >> 3));
            out1[(size_t)row * 32 + pos] = v;
        }
    }
}

// ---------------------------------------------------------------------------
// bf16 MFMA GEMM, 128x128 tile, BK=32, 256 threads = 4 waves (2x2 wave grid,
// each wave 64x64 via 4x4 mfma_16x16x32). N must be /128, M /128, K /32.
// ---------------------------------------------------------------------------
__global__ __launch_bounds__(256) void gemm_bf16_128(
    const unsigned short* __restrict__ A, const unsigned short* __restrict__ W,
    const float* __restrict__ bias,
    float* __restrict__ out0, float* __restrict__ out1,
    int M, int N, int K, int mode)
{
    __shared__ __align__(16) unsigned short sA[128 * 40];
    __shared__ __align__(16) unsigned short sB[128 * 40];
    const int bm = blockIdx.x * 128;
    const int bn = blockIdx.y * 128;
    const int tid  = threadIdx.x;
    const int wave = tid >> 6;
    const int lane = tid & 63;
    const int quad = lane >> 4;
    const int l16  = lane & 15;
    const int wr = wave >> 1, wc = wave & 1;
    const int r1  = tid >> 2;         // 0..63
    const int kof = (tid & 3) * 8;    // 0,8,16,24

    f32x4 acc[4][4];
    #pragma unroll
    for (int i = 0; i < 4; ++i)
        #pragma unroll
        for (int j = 0; j < 4; ++j) acc[i][j] = (f32x4)(0.f);

    for (int k0 = 0; k0 < K; k0 += 32) {
        *(bf16x8*)&sA[r1 * 40 + kof] =
            *(const bf16x8*)&A[(size_t)(bm + r1) * K + k0 + kof];
        *(bf16x8*)&sA[(r1 + 64) * 40 + kof] =
            *(const bf16x8*)&A[(size_t)(bm + r1 + 64) * K + k0 + kof];
        *(bf16x8*)&sB[r1 * 40 + kof] =
            *(const bf16x8*)&W[(size_t)(bn + r1) * K + k0 + kof];
        *(bf16x8*)&sB[(r1 + 64) * 40 + kof] =
            *(const bf16x8*)&W[(size_t)(bn + r1 + 64) * K + k0 + kof];
        __syncthreads();
        bf16x8 af[4], bf[4];
        #pragma unroll
        for (int mi = 0; mi < 4; ++mi)
            af[mi] = *(bf16x8*)&sA[(wr * 64 + mi * 16 + l16) * 40 + quad * 8];
        #pragma unroll
        for (int ni = 0; ni < 4; ++ni)
            bf[ni] = *(bf16x8*)&sB[(wc * 64 + ni * 16 + l16) * 40 + quad * 8];
        #pragma unroll
        for (int mi = 0; mi < 4; ++mi)
            #pragma unroll
            for (int ni = 0; ni < 4; ++ni)
                acc[mi][ni] = __builtin_amdgcn_mfma_f32_16x16x32_bf16(
                    af[mi], bf[ni], acc[mi][ni], 0, 0, 0);
        __syncthreads();
    }

    #pragma unroll
    for (int mi = 0; mi < 4; ++mi)
        #pragma unroll
        for (int ni = 0; ni < 4; ++ni) {
            int col = bn + wc * 64 + ni * 16 + l16;
            #pragma unroll
            for (int r = 0; r < 4; ++r) {
                int row = bm + wr * 64 + mi * 16 + quad * 4 + r;
                gemm_epilogue(mode, row, col, N, acc[mi][ni][r], bias, out0, out1);
            }
        }
}

// ---------------------------------------------------------------------------
// bf16 MFMA GEMM, 64x64 tile (kept for N=192 final GEMM).
// ---------------------------------------------------------------------------
__global__ __launch_bounds__(256) void gemm_bf16(
    const unsigned short* __restrict__ A, const unsigned short* __restrict__ W,
    const float* __restrict__ bias,
    float* __restrict__ out0, float* __restrict__ out1,
    int M, int N, int K, int mode)
{
    __shared__ __align__(16) unsigned short sA[64 * 40];
    __shared__ __align__(16) unsigned short sB[64 * 40];
    const int bm = blockIdx.x * 64;
    const int bn = blockIdx.y * 64;
    const int tid  = threadIdx.x;
    const int wave = tid >> 6;
    const int lane = tid & 63;
    const int quad = lane >> 4;
    const int l16  = lane & 15;

    const int lrow = tid >> 2;        // 0..63
    const int lkof = (tid & 3) * 8;   // 0,8,16,24

    f32x4 acc[4];
    #pragma unroll
    for (int t = 0; t < 4; ++t) acc[t] = (f32x4)(0.f);

    const int arow = (wave * 16 + l16) * 40 + quad * 8;

    for (int k0 = 0; k0 < K; k0 += 32) {
        *(bf16x8*)&sA[lrow * 40 + lkof] =
            *(const bf16x8*)&A[(size_t)(bm + lrow) * K + k0 + lkof];
        *(bf16x8*)&sB[lrow * 40 + lkof] =
            *(const bf16x8*)&W[(size_t)(bn + lrow) * K + k0 + lkof];
        __syncthreads();
        bf16x8 a = *(bf16x8*)&sA[arow];
        #pragma unroll
        for (int t = 0; t < 4; ++t) {
            bf16x8 b = *(bf16x8*)&sB[(t * 16 + l16) * 40 + quad * 8];
            acc[t] = __builtin_amdgcn_mfma_f32_16x16x32_bf16(a, b, acc[t], 0, 0, 0);
        }
        __syncthreads();
    }

    #pragma unroll
    for (int t = 0; t < 4; ++t) {
        int col = bn + t * 16 + l16;
        #pragma unroll
        for (int r = 0; r < 4; ++r) {
            int row = bm + wave * 16 + quad * 4 + r;
            gemm_epilogue(mode, row, col, N, acc[t][r], bias, out0, out1);
        }
    }
}

// ---------------------------------------------------------------------------
// Fused depthwise 3x3 convs (x and c) + bias + silu; writes xs (fp32) and
// s = silu(conv_x)+silu(conv_c) as bf16, SCATTERED to scan order.
// ---------------------------------------------------------------------------
__global__ __launch_bounds__(256) void dwconv2_scatter(
    const float* __restrict__ xin, const float* __restrict__ cin,
    const float* __restrict__ wx, const float* __restrict__ bx,
    const float* __restrict__ wc, const float* __restrict__ bc,
    const int* __restrict__ rev_scan_path,
    float* __restrict__ xs_buf, unsigned short* __restrict__ s_bf)
{
    const int tile = blockIdx.x;
    const int c0   = blockIdx.y * 64;
    const int b    = blockIdx.z;
    const int h0 = (tile >> 3) * 8, w0 = (tile & 7) * 8;
    __shared__ float smx[10 * 10 * 64];
    __shared__ float smc[10 * 10 * 64];
    __shared__ int   jtile[64];

    for (int idx = threadIdx.x; idx < 6400; idx += 256) {
        int pix = idx >> 6, ch = idx & 63;
        int py = pix / 10, px = pix - py * 10;
        int gh = h0 + py - 1, gw = w0 + px - 1;
        float vx = 0.f, vc = 0.f;
        if (gh >= 0 && gh < 64 && gw >= 0 && gw < 64) {
            size_t g = ((size_t)(b * LL + gh * 64 + gw)) * DI + c0 + ch;
            vx = xin[g]; vc = cin[g];
        }
        smx[idx] = vx; smc[idx] = vc;
    }
    if (threadIdx.x < 64) {
        int l = (h0 + (threadIdx.x >> 3)) * 64 + (w0 + (threadIdx.x & 7));
        jtile[threadIdx.x] = rev_scan_path[l];
    }
    __syncthreads();

    const int ch = threadIdx.x & 63;
    const int pq = threadIdx.x >> 6;
    float wrx[9], wrc[9];
    #pragma unroll
    for (int k = 0; k < 9; ++k) {
        wrx[k] = wx[(c0 + ch) * 9 + k];
        wrc[k] = wc[(c0 + ch) * 9 + k];
    }
    const float bvx = bx[c0 + ch];
    const float bvc = bc[c0 + ch];

    #pragma unroll
    for (int i = 0; i < 16; ++i) {
        int p  = pq * 16 + i;
        int ph = p >> 3, pw = p & 7;
        float ax = bvx, ac = bvc;
        #pragma unroll
        for (int ki = 0; ki < 3; ++ki)
            #pragma unroll
            for (int kj = 0; kj < 3; ++kj) {
                int si = ((ph + ki) * 10 + (pw + kj)) * 64 + ch;
                ax += wrx[ki * 3 + kj] * smx[si];
                ac += wrc[ki * 3 + kj] * smc[si];
            }
        float xv = silu_f(ax);
        float sv = xv + silu_f(ac);
        size_t o = ((size_t)(b * LL + jtile[p])) * DI + c0 + ch;
        xs_buf[o] = xv;
        s_bf[o]   = f2bf(sv);
    }
}

// ---------------------------------------------------------------------------
// Chunked parallel scan — Pass A. 8 lanes per channel, 2 states per lane.
// grid (NCHUNK, DI/32, BB), 256 threads. Output float2 [c][b][d][p] (p=0..7,
// holding states n=p and n=p+8).
// ---------------------------------------------------------------------------
__global__ __launch_bounds__(256) void scan_chunkA(
    const float* __restrict__ xs, const float* __restrict__ delta,
    const float* __restrict__ btct, const float* __restrict__ A_logs,
    float* __restrict__ chunkA, float* __restrict__ chunkB)
{
    const int c = blockIdx.x;
    const int g = blockIdx.y;
    const int b = blockIdx.z;
    const int t = threadIdx.x;
    const int grp = t >> 3, p = t & 7;
    const int d = g * 32 + grp;
    const float Av0 = -__expf(A_logs[d * NS + p]);
    const float Av1 = -__expf(A_logs[d * NS + p + 8]);
    const int j0 = c * LCHUNK;

    const float*  dl = delta + ((size_t)b * LL + j0) * DI + d;
    const float*  ul = xs    + ((size_t)b * LL + j0) * DI + d;
    const float2* bl = (const float2*)btct + ((size_t)b * LL + j0) * 16 + p * 2;

    float h0 = 0.f, h1 = 0.f, P0 = 1.f, P1 = 1.f;
    float dv[4], uv[4]; float2 bv[4];
    #pragma unroll
    for (int q = 0; q < 4; ++q) {
        dv[q] = dl[(size_t)q * DI]; uv[q] = ul[(size_t)q * DI]; bv[q] = bl[(size_t)q * 16];
    }
    for (int j = 0; j < LCHUNK; j += 4) {
        float nd[4], nu[4]; float2 nb[4];
        if (j + 4 < LCHUNK) {
            #pragma unroll
            for (int q = 0; q < 4; ++q) {
                int jj = j + 4 + q;
                nd[q] = dl[(size_t)jj * DI]; nu[q] = ul[(size_t)jj * DI]; nb[q] = bl[(size_t)jj * 16];
            }
        }
        #pragma unroll
        for (int q = 0; q < 4; ++q) {
            float e0 = __expf(dv[q] * Av0);
            float e1 = __expf(dv[q] * Av1);
            float du = dv[q] * uv[q];
            h0 = e0 * h0 + bv[q].x * du;
            h1 = e1 * h1 + bv[q].y * du;
            P0 *= e0; P1 *= e1;
        }
        #pragma unroll
        for (int q = 0; q < 4; ++q) { dv[q]=nd[q]; uv[q]=nu[q]; bv[q]=nb[q]; }
    }
    size_t idx = (((size_t)c * BB + b) * DI + d) * 8 + p;   // float2 index
    ((float2*)chunkA)[idx] = make_float2(P0, P1);
    ((float2*)chunkB)[idx] = make_float2(h0, h1);
}

// ---------------------------------------------------------------------------
// Pass B: serial combine over chunks (layout-agnostic elementwise).
// ---------------------------------------------------------------------------
__global__ __launch_bounds__(256) void scan_combine(
    const float* __restrict__ chunkA, const float* __restrict__ chunkB,
    float* __restrict__ hstart)
{
    const int gid = blockIdx.x * 256 + threadIdx.x;
    const size_t stride = (size_t)BB * DI * NS;
    float h = 0.f;
    float a = chunkA[gid], bv = chunkB[gid];
    for (int c = 0; c < NCHUNK; ++c) {
        float na = 0.f, nb = 0.f;
        if (c + 1 < NCHUNK) {
            na = chunkA[(size_t)(c + 1) * stride + gid];
            nb = chunkB[(size_t)(c + 1) * stride + gid];
        }
        hstart[(size_t)c * stride + gid] = h;
        h = a * h + bv;
        a = na; bv = nb;
    }
}

// ---------------------------------------------------------------------------
// Pass C: redo local scan seeded with hstart, emit y. Same mapping as pass A.
// btct packed as [j][p][B_p, B_{p+8}, C_p, C_{p+8}] -> one dwordx4 per step.
// ---------------------------------------------------------------------------
__global__ __launch_bounds__(256) void scan_chunkC(
    const float* __restrict__ xs, const float* __restrict__ delta,
    const float* __restrict__ btct,
    const float* __restrict__ A_logs, const float* __restrict__ Ds,
    const float* __restrict__ hstart,
    float* __restrict__ yt)
{
    const int c = blockIdx.x;
    const int g = blockIdx.y;
    const int b = blockIdx.z;
    const int t = threadIdx.x;
    const int grp = t >> 3, p = t & 7;
    const int d = g * 32 + grp;
    const float Av0 = -__expf(A_logs[d * NS + p]);
    const float Av1 = -__expf(A_logs[d * NS + p + 8]);
    const float Dv = Ds[d];
    const int j0 = c * LCHUNK;

    const float*  dl  = delta + ((size_t)b * LL + j0) * DI + d;
    const float*  ul  = xs    + ((size_t)b * LL + j0) * DI + d;
    const float4* bcl = (const float4*)btct + ((size_t)b * LL + j0) * 8 + p;
    float* yl = yt + ((size_t)b * LL + j0) * DI + d;

    float2 h = ((const float2*)hstart)[(((size_t)c * BB + b) * DI + d) * 8 + p];
    float h0 = h.x, h1 = h.y;

    float dv[4], uv[4]; float4 bc[4];
    #pragma unroll
    for (int q = 0; q < 4; ++q) {
        dv[q] = dl[(size_t)q * DI]; uv[q] = ul[(size_t)q * DI]; bc[q] = bcl[(size_t)q * 8];
    }
    for (int j = 0; j < LCHUNK; j += 4) {
        float nd[4], nu[4]; float4 nbc[4];
        if (j + 4 < LCHUNK) {
            #pragma unroll
            for (int q = 0; q < 4; ++q) {
                int jj = j + 4 + q;
                nd[q] = dl[(size_t)jj * DI]; nu[q] = ul[(size_t)jj * DI]; nbc[q] = bcl[(size_t)jj * 8];
            }
        }
        #pragma unroll
        for (int q = 0; q < 4; ++q) {
            float e0 = __expf(dv[q] * Av0);
            float e1 = __expf(dv[q] * Av1);
            float du = dv[q] * uv[q];
            h0 = e0 * h0 + bc[q].x * du;
            h1 = e1 * h1 + bc[q].y * du;
            float acc = h0 * bc[q].z + h1 * bc[q].w;
            acc += __shfl_xor(acc, 4, 8);
            acc += __shfl_xor(acc, 2, 8);
            acc += __shfl_xor(acc, 1, 8);
            if (p == 0) yl[(size_t)(j + q) * DI] = acc + uv[q] * Dv;
        }
        #pragma unroll
        for (int q = 0; q < 4; ++q) { dv[q]=nd[q]; uv[q]=nu[q]; bc[q]=nbc[q]; }
    }
}

// ---------------------------------------------------------------------------
// LayerNorm over d (384) + affine + z-mul; unpermute folded into write.
// ---------------------------------------------------------------------------
__global__ __launch_bounds__(128) void ln_mul(
    const float* __restrict__ yt, const float* __restrict__ z,
    const int* __restrict__ scan_path,
    const float* __restrict__ ln_w, const float* __restrict__ ln_b,
    unsigned short* __restrict__ yn)
{
    const int j = blockIdx.x;
    const int b = blockIdx.y;
    const int l = scan_path[j];
    const int t = threadIdx.x;
    const float* row = yt + ((size_t)(b * LL + j)) * DI;
    float v0 = row[t], v1 = row[t + 128], v2 = row[t + 256];
    float s  = v0 + v1 + v2;
    float s2 = v0*v0 + v1*v1 + v2*v2;
    #pragma unroll
    for (int off = 32; off > 0; off >>= 1) {
        s  += __shfl_down(s, off);
        s2 += __shfl_down(s2, off);
    }
    __shared__ float red[4];
    if ((t & 63) == 0) { red[(t >> 6) * 2] = s; red[(t >> 6) * 2 + 1] = s2; }
    __syncthreads();
    float S  = red[0] + red[2];
    float S2 = red[1] + red[3];
    float mu  = S * (1.0f / DI);
    float var = S2 * (1.0f / DI) - mu * mu;
    float inv = rsqrtf(var + 1e-5f);

    const float* zr = z + ((size_t)(b * LL + l)) * DI;
    unsigned short* o = yn + ((size_t)(b * LL + l)) * DI;
    o[t]       = f2bf(((v0 - mu) * inv * ln_w[t]       + ln_b[t])       * zr[t]);
    o[t + 128] = f2bf(((v1 - mu) * inv * ln_w[t + 128] + ln_b[t + 128]) * zr[t + 128]);
    o[t + 256] = f2bf(((v2 - mu) * inv * ln_w[t + 256] + ln_b[t + 256]) * zr[t + 256]);
}

// ---------------------------------------------------------------------------
extern "C" void kernel_launch(void* const* d_in, const int* in_sizes, int n_in,
                              void* d_out, int out_size, void* d_ws, size_t ws_size,
                              hipStream_t stream) {
    const float* x          = (const float*)d_in[0];
    const float* cond       = (const float*)d_in[1];
    const float* W_in       = (const float*)d_in[2];
    const float* W_con      = (const float*)d_in[3];
    const float* conv_w     = (const float*)d_in[4];
    const float* conv_b     = (const float*)d_in[5];
    const float* con_conv_w = (const float*)d_in[6];
    const float* con_conv_b = (const float*)d_in[7];
    const float* x_proj_w   = (const float*)d_in[8];
    const float* dt_proj_w  = (const float*)d_in[9];
    const float* dt_proj_b  = (const float*)d_in[10];
    const float* A_logs     = (const float*)d_in[11];
    const float* Ds         = (const float*)d_in[12];
    const float* ln_w       = (const float*)d_in[13];
    const float* ln_b       = (const float*)d_in[14];
    const float* W_out      = (const float*)d_in[15];
    const int*   scan_path  = (const int*)d_in[16];
    const int*   rev_path   = (const int*)d_in[17];

    float* ws = (float*)d_ws;
    const size_t S  = (size_t)BB * LL * DI;            // 3,145,728 floats
    const size_t SC = (size_t)NCHUNK * BB * DI * NS;   // 786,432 floats
    float* xa_pre  = ws + 0 * S;                       // reused later as yt
    float* z_silu  = ws + 1 * S;
    float* c_pre   = ws + 2 * S;                       // first half reused as yn_bf
    float* xs_buf  = ws + 3 * S;
    float* dl_buf  = ws + 4 * S;
    float* btct    = ws + 5 * S;                       // BB*LL*32 floats, packed
    float* chunkA  = btct + (size_t)BB * LL * 32;
    float* chunkB  = chunkA + SC;
    float* hstart  = chunkB + SC;
    float* bfpool  = hstart + SC;                      // bf16 staging area

    unsigned short* x_bf    = (unsigned short*)bfpool;             // ROWS*DM
    unsigned short* c_bf    = x_bf + (size_t)ROWS * DM;            // ROWS*DM
    unsigned short* s_bf    = x_bf;                                // ROWS*DI (overlays x_bf+c_bf, dead by then)
    unsigned short* w_in_bf  = c_bf + (size_t)ROWS * DM;           // 768*192
    unsigned short* w_con_bf = w_in_bf + 768 * DM;                 // 384*192
    unsigned short* w_out_bf = w_con_bf + 384 * DM;                // 192*384
    unsigned short* wcomb_bf = w_out_bf + 192 * DI;                // 512*384
    unsigned short* yn_bf    = (unsigned short*)c_pre;             // ROWS*DI
    float* yt = xa_pre;

    // 0) casts + combined weight
    cast_bf16<<<(ROWS * DM / 4 + 255) / 256, 256, 0, stream>>>(x, x_bf, ROWS * DM / 4);
    cast_bf16<<<(ROWS * DM / 4 + 255) / 256, 256, 0, stream>>>(cond, c_bf, ROWS * DM / 4);
    cast_weights<<<(73728 + 255) / 256, 256, 0, stream>>>(
        W_in, W_con, W_out, w_in_bf, w_con_bf, w_out_bf);
    make_wcomb<<<(NCOMB * DI + 255) / 256, 256, 0, stream>>>(x_proj_w, dt_proj_w, wcomb_bf);

    // 1) xz = x @ W_in.T  -> xa_pre (raw), z_silu (silu)
    gemm_bf16_128<<<dim3(ROWS / 128, 768 / 128), 256, 0, stream>>>(
        x_bf, w_in_bf, nullptr, xa_pre, z_silu, ROWS, 768, DM, 0);
    // 2) c = cond @ W_con.T -> c_pre
    gemm_bf16_128<<<dim3(ROWS / 128, 384 / 128), 256, 0, stream>>>(
        c_bf, w_con_bf, nullptr, c_pre, nullptr, ROWS, 384, DM, 1);
    // 3) fused depthwise convs + silu + scatter to scan order (s in bf16)
    dwconv2_scatter<<<dim3(64, 6, BB), 256, 0, stream>>>(
        xa_pre, c_pre, conv_w, conv_b, con_conv_w, con_conv_b,
        rev_path, xs_buf, s_bf);
    // 4) combined GEMM: delta (softplus) + packed btct
    gemm_bf16_128<<<dim3(ROWS / 128, NCOMB / 128), 256, 0, stream>>>(
        s_bf, wcomb_bf, dt_proj_b, dl_buf, btct, ROWS, NCOMB, DI, 2);
    // 5) chunked parallel scan (3 passes)
    scan_chunkA<<<dim3(NCHUNK, DI / 32, BB), 256, 0, stream>>>(
        xs_buf, dl_buf, btct, A_logs, chunkA, chunkB);
    scan_combine<<<(BB * DI * NS) / 256, 256, 0, stream>>>(chunkA, chunkB, hstart);
    scan_chunkC<<<dim3(NCHUNK, DI / 32, BB), 256, 0, stream>>>(
        xs_buf, dl_buf, btct, A_logs, Ds, hstart, yt);
    // 6) LN + z-mul (unpermute folded in), yn in bf16
    ln_mul<<<dim3(LL, BB), 128, 0, stream>>>(yt, z_silu, scan_path, ln_w, ln_b, yn_bf);
    // 7) out = yn @ W_out.T
    gemm_bf16<<<dim3(ROWS / 64, 192 / 64), 256, 0, stream>>>(
        yn_bf, w_out_bf, nullptr, (float*)d_out, nullptr, ROWS, DM, DI, 1);
}

// Round 7
// 231.022 us; speedup vs baseline: 1.2398x; 1.2398x over previous
//
#include <hip/hip_runtime.h>
#include <math.h>

// Problem constants
#define BB 2
#define HH 64
#define WW 64
#define DM 192
#define DI 384
#define NS 16
#define DTR 12
#define LL 4096
#define ROWS (BB*LL)   // 8192
#define NCHUNK 64
#define LCHUNK 64      // NCHUNK*LCHUNK == LL
#define NCOMB 448      // padded combined-weight rows (416 real), /64 for 64-tile

typedef __attribute__((ext_vector_type(8))) short bf16x8;
typedef __attribute__((ext_vector_type(4))) float f32x4;

__device__ __forceinline__ float silu_f(float v) {
    return v / (1.0f + __expf(-v));
}

// fp32 -> bf16 (RNE) bit trick
__device__ __forceinline__ unsigned short f2bf(float f) {
    union { float f; unsigned int u; } c; c.f = f;
    unsigned int u = c.u;
    u += 0x7fffu + ((u >> 16) & 1u);
    return (unsigned short)(u >> 16);
}

// ---------------------------------------------------------------------------
// Cast a float array to bf16 (vectorized by 4). n must be /4.
// ---------------------------------------------------------------------------
__global__ __launch_bounds__(256) void cast_bf16(
    const float* __restrict__ in, unsigned short* __restrict__ out, int n4)
{
    int i = blockIdx.x * 256 + threadIdx.x;
    if (i >= n4) return;
    float4 v = ((const float4*)in)[i];
    ushort4 o;
    o.x = f2bf(v.x); o.y = f2bf(v.y); o.z = f2bf(v.z); o.w = f2bf(v.w);
    ((ushort4*)out)[i] = o;
}

// Cast the three static weights in one launch.
__global__ __launch_bounds__(256) void cast_weights(
    const float* __restrict__ w_in, const float* __restrict__ w_con,
    const float* __restrict__ w_out,
    unsigned short* __restrict__ w_in_bf, unsigned short* __restrict__ w_con_bf,
    unsigned short* __restrict__ w_out_bf)
{
    int i = blockIdx.x * 256 + threadIdx.x;   // float4 index, < 73728
    if (i >= 73728) return;
    const float4* src; ushort4* dst; int off;
    if (i < 36864)      { src = (const float4*)w_in;  dst = (ushort4*)w_in_bf;  off = i; }
    else if (i < 55296) { src = (const float4*)w_con; dst = (ushort4*)w_con_bf; off = i - 36864; }
    else                { src = (const float4*)w_out; dst = (ushort4*)w_out_bf; off = i - 55296; }
    float4 v = src[off];
    ushort4 o;
    o.x = f2bf(v.x); o.y = f2bf(v.y); o.z = f2bf(v.z); o.w = f2bf(v.w);
    dst[off] = o;
}

// ---------------------------------------------------------------------------
// Build combined weight Wc[448][384] in bf16:
//   rows 0..383:   sum_{r<12} dt_w[d][r] * x_proj_w[r][k]
//   rows 384..415: x_proj_w[12+c][k];  rows 416..447: 0
// ---------------------------------------------------------------------------
__global__ __launch_bounds__(256) void make_wcomb(
    const float* __restrict__ x_proj_w,   // (44,384)
    const float* __restrict__ dt_w,       // (384,12)
    unsigned short* __restrict__ wc)
{
    int idx = blockIdx.x * 256 + threadIdx.x;   // < 448*384
    if (idx >= NCOMB * DI) return;
    int row = idx / DI, k = idx - row * DI;
    float v = 0.f;
    if (row < 384) {
        const float* dw = dt_w + row * DTR;
        #pragma unroll
        for (int r = 0; r < DTR; ++r) v += dw[r] * x_proj_w[r * DI + k];
    } else if (row < 416) {
        v = x_proj_w[(12 + (row - 384)) * DI + k];
    }
    wc[idx] = f2bf(v);
}

// ---------------------------------------------------------------------------
// Shared epilogue semantics:
// mode 0: N=768 split -> out0[row*384+col] raw (col<384), out1 = silu
// mode 1: plain out0[row*N+col]
// mode 2: col<384 -> out0 = softplus(v+bias[col]);
//         col in [384,400): B_n (n=col-384) -> out1[row*32 + (n&7)*4 + (n>>3)]
//         col in [400,416): C_n (n=col-400) -> out1[row*32 + (n&7)*4 + 2 + (n>>3)]
//         col>=416 dropped.
// ---------------------------------------------------------------------------
__device__ __forceinline__ void gemm_epilogue(
    int mode, int row, int col, int N, float v,
    const float* __restrict__ bias,
    float* __restrict__ out0, float* __restrict__ out1)
{
    if (mode == 0) {
        if (col < 384) out0[(size_t)row * 384 + col] = v;
        else           out1[(size_t)row * 384 + (col - 384)] = silu_f(v);
    } else if (mode == 1) {
        out0[(size_t)row * N + col] = v;
    } else {
        if (col < 384) {
            float a = v + bias[col];
            out0[(size_t)row * 384 + col] = (a > 20.f) ? a : log1pf(__expf(a));
        } else if (col < 416) {
            int idx = col - 384;
            int pos = (idx < 16) ? ((idx & 7) * 4 + (idx >> 3))
                                 : (((idx - 16) & 7) * 4 + 2 + ((idx - 16) >> 3));
            out1[(size_t)row * 32 + pos] = v;
        }
    }
}

// ---------------------------------------------------------------------------
// bf16 MFMA GEMM, 64x64 tile, BK=32, 256 threads (4 waves; wave w -> rows
// w*16..w*16+15). Proven shape for these skinny-K GEMMs (grid >= 3 blocks/CU).
// ---------------------------------------------------------------------------
__global__ __launch_bounds__(256) void gemm_bf16(
    const unsigned short* __restrict__ A, const unsigned short* __restrict__ W,
    const float* __restrict__ bias,
    float* __restrict__ out0, float* __restrict__ out1,
    int M, int N, int K, int mode)
{
    __shared__ __align__(16) unsigned short sA[64 * 40];  // row stride 40 -> only free 2-way aliasing
    __shared__ __align__(16) unsigned short sB[64 * 40];
    const int bm = blockIdx.x * 64;
    const int bn = blockIdx.y * 64;
    const int tid  = threadIdx.x;
    const int wave = tid >> 6;
    const int lane = tid & 63;
    const int quad = lane >> 4;
    const int l16  = lane & 15;

    const int lrow = tid >> 2;        // 0..63
    const int lkof = (tid & 3) * 8;   // 0,8,16,24 (bf16 elems)

    f32x4 acc[4];
    #pragma unroll
    for (int t = 0; t < 4; ++t) acc[t] = (f32x4)(0.f);

    const int arow = (wave * 16 + l16) * 40 + quad * 8;

    for (int k0 = 0; k0 < K; k0 += 32) {
        *(bf16x8*)&sA[lrow * 40 + lkof] =
            *(const bf16x8*)&A[(size_t)(bm + lrow) * K + k0 + lkof];
        *(bf16x8*)&sB[lrow * 40 + lkof] =
            *(const bf16x8*)&W[(size_t)(bn + lrow) * K + k0 + lkof];
        __syncthreads();
        bf16x8 a = *(bf16x8*)&sA[arow];
        #pragma unroll
        for (int t = 0; t < 4; ++t) {
            bf16x8 b = *(bf16x8*)&sB[(t * 16 + l16) * 40 + quad * 8];
            acc[t] = __builtin_amdgcn_mfma_f32_16x16x32_bf16(a, b, acc[t], 0, 0, 0);
        }
        __syncthreads();
    }

    #pragma unroll
    for (int t = 0; t < 4; ++t) {
        int col = bn + t * 16 + l16;
        #pragma unroll
        for (int r = 0; r < 4; ++r) {
            int row = bm + wave * 16 + quad * 4 + r;
            gemm_epilogue(mode, row, col, N, acc[t][r], bias, out0, out1);
        }
    }
}

// ---------------------------------------------------------------------------
// Fused depthwise 3x3 convs (x and c) + bias + silu; writes xs (fp32) and
// s = silu(conv_x)+silu(conv_c) as bf16, SCATTERED to scan order.
// ---------------------------------------------------------------------------
__global__ __launch_bounds__(256) void dwconv2_scatter(
    const float* __restrict__ xin, const float* __restrict__ cin,
    const float* __restrict__ wx, const float* __restrict__ bx,
    const float* __restrict__ wc, const float* __restrict__ bc,
    const int* __restrict__ rev_scan_path,
    float* __restrict__ xs_buf, unsigned short* __restrict__ s_bf)
{
    const int tile = blockIdx.x;
    const int c0   = blockIdx.y * 64;
    const int b    = blockIdx.z;
    const int h0 = (tile >> 3) * 8, w0 = (tile & 7) * 8;
    __shared__ float smx[10 * 10 * 64];
    __shared__ float smc[10 * 10 * 64];
    __shared__ int   jtile[64];

    for (int idx = threadIdx.x; idx < 6400; idx += 256) {
        int pix = idx >> 6, ch = idx & 63;
        int py = pix / 10, px = pix - py * 10;
        int gh = h0 + py - 1, gw = w0 + px - 1;
        float vx = 0.f, vc = 0.f;
        if (gh >= 0 && gh < 64 && gw >= 0 && gw < 64) {
            size_t g = ((size_t)(b * LL + gh * 64 + gw)) * DI + c0 + ch;
            vx = xin[g]; vc = cin[g];
        }
        smx[idx] = vx; smc[idx] = vc;
    }
    if (threadIdx.x < 64) {
        int l = (h0 + (threadIdx.x >> 3)) * 64 + (w0 + (threadIdx.x & 7));
        jtile[threadIdx.x] = rev_scan_path[l];
    }
    __syncthreads();

    const int ch = threadIdx.x & 63;
    const int pq = threadIdx.x >> 6;
    float wrx[9], wrc[9];
    #pragma unroll
    for (int k = 0; k < 9; ++k) {
        wrx[k] = wx[(c0 + ch) * 9 + k];
        wrc[k] = wc[(c0 + ch) * 9 + k];
    }
    const float bvx = bx[c0 + ch];
    const float bvc = bc[c0 + ch];

    #pragma unroll
    for (int i = 0; i < 16; ++i) {
        int p  = pq * 16 + i;
        int ph = p >> 3, pw = p & 7;
        float ax = bvx, ac = bvc;
        #pragma unroll
        for (int ki = 0; ki < 3; ++ki)
            #pragma unroll
            for (int kj = 0; kj < 3; ++kj) {
                int si = ((ph + ki) * 10 + (pw + kj)) * 64 + ch;
                ax += wrx[ki * 3 + kj] * smx[si];
                ac += wrc[ki * 3 + kj] * smc[si];
            }
        float xv = silu_f(ax);
        float sv = xv + silu_f(ac);
        size_t o = ((size_t)(b * LL + jtile[p])) * DI + c0 + ch;
        xs_buf[o] = xv;
        s_bf[o]   = f2bf(sv);
    }
}

// ---------------------------------------------------------------------------
// Chunked parallel scan — Pass A. 8 lanes per channel, 2 states per lane.
// grid (NCHUNK, DI/32, BB), 256 threads. Output float2 [c][b][d][p] (p=0..7,
// holding states n=p and n=p+8).
// ---------------------------------------------------------------------------
__global__ __launch_bounds__(256) void scan_chunkA(
    const float* __restrict__ xs, const float* __restrict__ delta,
    const float* __restrict__ btct, const float* __restrict__ A_logs,
    float* __restrict__ chunkA, float* __restrict__ chunkB)
{
    const int c = blockIdx.x;
    const int g = blockIdx.y;
    const int b = blockIdx.z;
    const int t = threadIdx.x;
    const int grp = t >> 3, p = t & 7;
    const int d = g * 32 + grp;
    const float Av0 = -__expf(A_logs[d * NS + p]);
    const float Av1 = -__expf(A_logs[d * NS + p + 8]);
    const int j0 = c * LCHUNK;

    const float*  dl = delta + ((size_t)b * LL + j0) * DI + d;
    const float*  ul = xs    + ((size_t)b * LL + j0) * DI + d;
    const float2* bl = (const float2*)btct + ((size_t)b * LL + j0) * 16 + p * 2;

    float h0 = 0.f, h1 = 0.f, P0 = 1.f, P1 = 1.f;
    float dv[4], uv[4]; float2 bv[4];
    #pragma unroll
    for (int q = 0; q < 4; ++q) {
        dv[q] = dl[(size_t)q * DI]; uv[q] = ul[(size_t)q * DI]; bv[q] = bl[(size_t)q * 16];
    }
    for (int j = 0; j < LCHUNK; j += 4) {
        float nd[4], nu[4]; float2 nb[4];
        if (j + 4 < LCHUNK) {
            #pragma unroll
            for (int q = 0; q < 4; ++q) {
                int jj = j + 4 + q;
                nd[q] = dl[(size_t)jj * DI]; nu[q] = ul[(size_t)jj * DI]; nb[q] = bl[(size_t)jj * 16];
            }
        }
        #pragma unroll
        for (int q = 0; q < 4; ++q) {
            float e0 = __expf(dv[q] * Av0);
            float e1 = __expf(dv[q] * Av1);
            float du = dv[q] * uv[q];
            h0 = e0 * h0 + bv[q].x * du;
            h1 = e1 * h1 + bv[q].y * du;
            P0 *= e0; P1 *= e1;
        }
        #pragma unroll
        for (int q = 0; q < 4; ++q) { dv[q]=nd[q]; uv[q]=nu[q]; bv[q]=nb[q]; }
    }
    size_t idx = (((size_t)c * BB + b) * DI + d) * 8 + p;   // float2 index
    ((float2*)chunkA)[idx] = make_float2(P0, P1);
    ((float2*)chunkB)[idx] = make_float2(h0, h1);
}

// ---------------------------------------------------------------------------
// Pass B: serial combine over chunks (layout-agnostic elementwise).
// ---------------------------------------------------------------------------
__global__ __launch_bounds__(256) void scan_combine(
    const float* __restrict__ chunkA, const float* __restrict__ chunkB,
    float* __restrict__ hstart)
{
    const int gid = blockIdx.x * 256 + threadIdx.x;
    const size_t stride = (size_t)BB * DI * NS;
    float h = 0.f;
    float a = chunkA[gid], bv = chunkB[gid];
    for (int c = 0; c < NCHUNK; ++c) {
        float na = 0.f, nb = 0.f;
        if (c + 1 < NCHUNK) {
            na = chunkA[(size_t)(c + 1) * stride + gid];
            nb = chunkB[(size_t)(c + 1) * stride + gid];
        }
        hstart[(size_t)c * stride + gid] = h;
        h = a * h + bv;
        a = na; bv = nb;
    }
}

// ---------------------------------------------------------------------------
// Pass C: redo local scan seeded with hstart, emit y. Same mapping as pass A.
// btct packed as [j][p][B_p, B_{p+8}, C_p, C_{p+8}] -> one dwordx4 per step.
// ---------------------------------------------------------------------------
__global__ __launch_bounds__(256) void scan_chunkC(
    const float* __restrict__ xs, const float* __restrict__ delta,
    const float* __restrict__ btct,
    const float* __restrict__ A_logs, const float* __restrict__ Ds,
    const float* __restrict__ hstart,
    float* __restrict__ yt)
{
    const int c = blockIdx.x;
    const int g = blockIdx.y;
    const int b = blockIdx.z;
    const int t = threadIdx.x;
    const int grp = t >> 3, p = t & 7;
    const int d = g * 32 + grp;
    const float Av0 = -__expf(A_logs[d * NS + p]);
    const float Av1 = -__expf(A_logs[d * NS + p + 8]);
    const float Dv = Ds[d];
    const int j0 = c * LCHUNK;

    const float*  dl  = delta + ((size_t)b * LL + j0) * DI + d;
    const float*  ul  = xs    + ((size_t)b * LL + j0) * DI + d;
    const float4* bcl = (const float4*)btct + ((size_t)b * LL + j0) * 8 + p;
    float* yl = yt + ((size_t)b * LL + j0) * DI + d;

    float2 h = ((const float2*)hstart)[(((size_t)c * BB + b) * DI + d) * 8 + p];
    float h0 = h.x, h1 = h.y;

    float dv[4], uv[4]; float4 bc[4];
    #pragma unroll
    for (int q = 0; q < 4; ++q) {
        dv[q] = dl[(size_t)q * DI]; uv[q] = ul[(size_t)q * DI]; bc[q] = bcl[(size_t)q * 8];
    }
    for (int j = 0; j < LCHUNK; j += 4) {
        float nd[4], nu[4]; float4 nbc[4];
        if (j + 4 < LCHUNK) {
            #pragma unroll
            for (int q = 0; q < 4; ++q) {
                int jj = j + 4 + q;
                nd[q] = dl[(size_t)jj * DI]; nu[q] = ul[(size_t)jj * DI]; nbc[q] = bcl[(size_t)jj * 8];
            }
        }
        #pragma unroll
        for (int q = 0; q < 4; ++q) {
            float e0 = __expf(dv[q] * Av0);
            float e1 = __expf(dv[q] * Av1);
            float du = dv[q] * uv[q];
            h0 = e0 * h0 + bc[q].x * du;
            h1 = e1 * h1 + bc[q].y * du;
            float acc = h0 * bc[q].z + h1 * bc[q].w;
            acc += __shfl_xor(acc, 4, 8);
            acc += __shfl_xor(acc, 2, 8);
            acc += __shfl_xor(acc, 1, 8);
            if (p == 0) yl[(size_t)(j + q) * DI] = acc + uv[q] * Dv;
        }
        #pragma unroll
        for (int q = 0; q < 4; ++q) { dv[q]=nd[q]; uv[q]=nu[q]; bc[q]=nbc[q]; }
    }
}

// ---------------------------------------------------------------------------
// LayerNorm over d (384) + affine + z-mul; unpermute folded into write.
// ---------------------------------------------------------------------------
__global__ __launch_bounds__(128) void ln_mul(
    const float* __restrict__ yt, const float* __restrict__ z,
    const int* __restrict__ scan_path,
    const float* __restrict__ ln_w, const float* __restrict__ ln_b,
    unsigned short* __restrict__ yn)
{
    const int j = blockIdx.x;
    const int b = blockIdx.y;
    const int l = scan_path[j];
    const int t = threadIdx.x;
    const float* row = yt + ((size_t)(b * LL + j)) * DI;
    float v0 = row[t], v1 = row[t + 128], v2 = row[t + 256];
    float s  = v0 + v1 + v2;
    float s2 = v0*v0 + v1*v1 + v2*v2;
    #pragma unroll
    for (int off = 32; off > 0; off >>= 1) {
        s  += __shfl_down(s, off);
        s2 += __shfl_down(s2, off);
    }
    __shared__ float red[4];
    if ((t & 63) == 0) { red[(t >> 6) * 2] = s; red[(t >> 6) * 2 + 1] = s2; }
    __syncthreads();
    float S  = red[0] + red[2];
    float S2 = red[1] + red[3];
    float mu  = S * (1.0f / DI);
    float var = S2 * (1.0f / DI) - mu * mu;
    float inv = rsqrtf(var + 1e-5f);

    const float* zr = z + ((size_t)(b * LL + l)) * DI;
    unsigned short* o = yn + ((size_t)(b * LL + l)) * DI;
    o[t]       = f2bf(((v0 - mu) * inv * ln_w[t]       + ln_b[t])       * zr[t]);
    o[t + 128] = f2bf(((v1 - mu) * inv * ln_w[t + 128] + ln_b[t + 128]) * zr[t + 128]);
    o[t + 256] = f2bf(((v2 - mu) * inv * ln_w[t + 256] + ln_b[t + 256]) * zr[t + 256]);
}

// ---------------------------------------------------------------------------
extern "C" void kernel_launch(void* const* d_in, const int* in_sizes, int n_in,
                              void* d_out, int out_size, void* d_ws, size_t ws_size,
                              hipStream_t stream) {
    const float* x          = (const float*)d_in[0];
    const float* cond       = (const float*)d_in[1];
    const float* W_in       = (const float*)d_in[2];
    const float* W_con      = (const float*)d_in[3];
    const float* conv_w     = (const float*)d_in[4];
    const float* conv_b     = (const float*)d_in[5];
    const float* con_conv_w = (const float*)d_in[6];
    const float* con_conv_b = (const float*)d_in[7];
    const float* x_proj_w   = (const float*)d_in[8];
    const float* dt_proj_w  = (const float*)d_in[9];
    const float* dt_proj_b  = (const float*)d_in[10];
    const float* A_logs     = (const float*)d_in[11];
    const float* Ds         = (const float*)d_in[12];
    const float* ln_w       = (const float*)d_in[13];
    const float* ln_b       = (const float*)d_in[14];
    const float* W_out      = (const float*)d_in[15];
    const int*   scan_path  = (const int*)d_in[16];
    const int*   rev_path   = (const int*)d_in[17];

    float* ws = (float*)d_ws;
    const size_t S  = (size_t)BB * LL * DI;            // 3,145,728 floats
    const size_t SC = (size_t)NCHUNK * BB * DI * NS;   // 786,432 floats
    float* xa_pre  = ws + 0 * S;                       // reused later as yt
    float* z_silu  = ws + 1 * S;
    float* c_pre   = ws + 2 * S;                       // first half reused as yn_bf
    float* xs_buf  = ws + 3 * S;
    float* dl_buf  = ws + 4 * S;
    float* btct    = ws + 5 * S;                       // BB*LL*32 floats, packed
    float* chunkA  = btct + (size_t)BB * LL * 32;
    float* chunkB  = chunkA + SC;
    float* hstart  = chunkB + SC;
    float* bfpool  = hstart + SC;                      // bf16 staging area

    unsigned short* x_bf    = (unsigned short*)bfpool;             // ROWS*DM
    unsigned short* c_bf    = x_bf + (size_t)ROWS * DM;            // ROWS*DM
    unsigned short* s_bf    = x_bf;                                // ROWS*DI (overlays x_bf+c_bf, dead by then)
    unsigned short* w_in_bf  = c_bf + (size_t)ROWS * DM;           // 768*192
    unsigned short* w_con_bf = w_in_bf + 768 * DM;                 // 384*192
    unsigned short* w_out_bf = w_con_bf + 384 * DM;                // 192*384
    unsigned short* wcomb_bf = w_out_bf + 192 * DI;                // 448*384
    unsigned short* yn_bf    = (unsigned short*)c_pre;             // ROWS*DI
    float* yt = xa_pre;

    // 0) casts + combined weight
    cast_bf16<<<(ROWS * DM / 4 + 255) / 256, 256, 0, stream>>>(x, x_bf, ROWS * DM / 4);
    cast_bf16<<<(ROWS * DM / 4 + 255) / 256, 256, 0, stream>>>(cond, c_bf, ROWS * DM / 4);
    cast_weights<<<(73728 + 255) / 256, 256, 0, stream>>>(
        W_in, W_con, W_out, w_in_bf, w_con_bf, w_out_bf);
    make_wcomb<<<(NCOMB * DI + 255) / 256, 256, 0, stream>>>(x_proj_w, dt_proj_w, wcomb_bf);

    // 1) xz = x @ W_in.T  -> xa_pre (raw), z_silu (silu)
    gemm_bf16<<<dim3(ROWS / 64, 768 / 64), 256, 0, stream>>>(
        x_bf, w_in_bf, nullptr, xa_pre, z_silu, ROWS, 768, DM, 0);
    // 2) c = cond @ W_con.T -> c_pre
    gemm_bf16<<<dim3(ROWS / 64, 384 / 64), 256, 0, stream>>>(
        c_bf, w_con_bf, nullptr, c_pre, nullptr, ROWS, 384, DM, 1);
    // 3) fused depthwise convs + silu + scatter to scan order (s in bf16)
    dwconv2_scatter<<<dim3(64, 6, BB), 256, 0, stream>>>(
        xa_pre, c_pre, conv_w, conv_b, con_conv_w, con_conv_b,
        rev_path, xs_buf, s_bf);
    // 4) combined GEMM: delta (softplus) + packed btct
    gemm_bf16<<<dim3(ROWS / 64, NCOMB / 64), 256, 0, stream>>>(
        s_bf, wcomb_bf, dt_proj_b, dl_buf, btct, ROWS, NCOMB, DI, 2);
    // 5) chunked parallel scan (3 passes)
    scan_chunkA<<<dim3(NCHUNK, DI / 32, BB), 256, 0, stream>>>(
        xs_buf, dl_buf, btct, A_logs, chunkA, chunkB);
    scan_combine<<<(BB * DI * NS) / 256, 256, 0, stream>>>(chunkA, chunkB, hstart);
    scan_chunkC<<<dim3(NCHUNK, DI / 32, BB), 256, 0, stream>>>(
        xs_buf, dl_buf, btct, A_logs, Ds, hstart, yt);
    // 6) LN + z-mul (unpermute folded in), yn in bf16
    ln_mul<<<dim3(LL, BB), 128, 0, stream>>>(yt, z_silu, scan_path, ln_w, ln_b, yn_bf);
    // 7) out = yn @ W_out.T
    gemm_bf16<<<dim3(ROWS / 64, 192 / 64), 256, 0, stream>>>(
        yn_bf, w_out_bf, nullptr, (float*)d_out, nullptr, ROWS, DM, DI, 1);
}